// Round 19
// baseline (512.316 us; speedup 1.0000x reference)
//
#include <hip/hip_runtime.h>

#define EPS 1e-16f

typedef __attribute__((ext_vector_type(8))) short short8;
typedef __attribute__((ext_vector_type(4))) float f32x4;

// ---------- bf16 <-> fp32 (internal storage only) ----------
__device__ __forceinline__ float b2f(unsigned short u) {
    return __uint_as_float(((unsigned)u) << 16);
}
__device__ __forceinline__ unsigned short f2b(float f) {
    unsigned u = __float_as_uint(f);
    u += 0x7fffu + ((u >> 16) & 1u);  // round-to-nearest-even
    return (unsigned short)(u >> 16);
}

// ---------- async global->LDS (16B per lane; dst = base + lane*16) ----------
typedef __attribute__((address_space(3))) void lds_vp;
typedef __attribute__((address_space(1))) const void glb_vp;
__device__ __forceinline__ void load_lds16(const unsigned short* g,
                                           unsigned short* l) {
    __builtin_amdgcn_global_load_lds((glb_vp*)g, (lds_vp*)l, 16, 0, 0);
}

// ---------------------------- CSR build ----------------------------
__global__ void init_deg_kernel(int* deg, int N) {
    int i = blockIdx.x * blockDim.x + threadIdx.x;
    if (i < N) deg[i] = 1;  // self-loop
}

__global__ void hist_kernel(const int* __restrict__ ei, int E, int N, int* deg) {
    int e = blockIdx.x * blockDim.x + threadIdx.x;
    if (e < E) {
        int d = ei[E + e];
        if ((unsigned)d < (unsigned)N) atomicAdd(&deg[d], 1);
    }
}

__global__ void scan_block_kernel(const int* __restrict__ deg,
                                  int* __restrict__ rowst,
                                  int* __restrict__ bsum, int N) {
    __shared__ int s[256];
    int t = threadIdx.x, b = blockIdx.x;
    int i = b * 256 + t;
    s[t] = (i < N) ? deg[i] : 0;
    __syncthreads();
    for (int o = 1; o < 256; o <<= 1) {
        int a = (t >= o) ? s[t - o] : 0;
        __syncthreads();
        s[t] += a;
        __syncthreads();
    }
    if (i < N) rowst[i + 1] = s[t];
    if (t == 255) bsum[b] = s[255];
}

__global__ void scan_top_kernel(const int* __restrict__ bsum,
                                int* __restrict__ boff, int NB) {
    __shared__ int psum[65];
    int t = threadIdx.x;  // 64
    int chunk = (NB + 63) / 64;
    int lo = t * chunk, hi = lo + chunk;
    if (lo > NB) lo = NB;
    if (hi > NB) hi = NB;
    int s = 0;
    for (int i = lo; i < hi; i++) s += bsum[i];
    psum[t + 1] = s;
    __syncthreads();
    if (t == 0) {
        psum[0] = 0;
        for (int i = 1; i <= 64; i++) psum[i] += psum[i - 1];
    }
    __syncthreads();
    int run = psum[t];
    for (int i = lo; i < hi; i++) {
        boff[i] = run;  // exclusive
        run += bsum[i];
    }
}

// fused: add block offsets + place self-loop + init cursor
// rowst[i] (row start) = (rowst[i+1]+boff) - deg[i]
__global__ void scan_finish_kernel(int* __restrict__ rowst,
                                   const int* __restrict__ boff,
                                   const int* __restrict__ deg,
                                   int* __restrict__ srcs,
                                   int* __restrict__ cursor, int N) {
    int i = blockIdx.x * 256 + threadIdx.x;
    if (i == 0) rowst[0] = 0;
    if (i < N) {
        int incl = rowst[i + 1] + boff[blockIdx.x];
        rowst[i + 1] = incl;
        int st = incl - deg[i];
        srcs[st] = i;  // self-loop at row head
        cursor[i] = st + 1;
    }
}

// resolve source node at CSR build time
__global__ void scatter_kernel(const int* __restrict__ ei, int E, int N,
                               int* cursor, int* srcs) {
    int e = blockIdx.x * blockDim.x + threadIdx.x;
    if (e < E) {
        int d = ei[E + e];
        if ((unsigned)d < (unsigned)N) {
            int p = atomicAdd(&cursor[d], 1);
            int s = ei[e];
            if ((unsigned)s >= (unsigned)N) s = d;
            srcs[p] = s;
        }
    }
}

// ---------------- merged weight prep: wt2, wt3, w1sk ----------------
// wt2 [512][1024] <- W2 [1024,512]; wt3 [128][512] <- W3 [512,128];
// w1sk [8][128][32]: small-K B for layer-1 (K window base = min(16h,96)).
__global__ void wprep_kernel(const float* __restrict__ W1,
                             const float* __restrict__ W2,
                             const float* __restrict__ W3,
                             unsigned short* __restrict__ wt2,
                             unsigned short* __restrict__ wt3,
                             unsigned short* __restrict__ w1sk) {
    int i = blockIdx.x * blockDim.x + threadIdx.x;
    if (i < 1024 * 512) {
        int k = i / 512, n = i % 512;
        wt2[(size_t)n * 1024 + k] = f2b(W2[i]);
    } else if (i < 1024 * 512 + 512 * 128) {
        int j = i - 1024 * 512;
        int k = j / 128, n = j % 128;
        wt3[(size_t)n * 512 + k] = f2b(W3[j]);
    } else if (i < 1024 * 512 + 512 * 128 + 8 * 128 * 32) {
        int q = i - (1024 * 512 + 512 * 128);
        int h = q >> 12, rem = q & 4095;
        int c = rem >> 5, kk = rem & 31;
        int off = (h == 7) ? 16 : 0;  // 16h - min(16h,96)
        float v = 0.f;
        int k = kk - off;
        if (k >= 0 && k < 11) v = W1[k * 1024 + h * 128 + c];
        w1sk[q] = f2b(v);
    }
}

// ---------------- layer-1 logits (wa1 recomputed per block in LDS) ----------------
__global__ void al1_kernel(const float* __restrict__ x,
                           const float* __restrict__ W1,
                           const float* __restrict__ a1s,
                           const float* __restrict__ a1d,
                           float* __restrict__ als, float* __restrict__ ald,
                           int N) {
    __shared__ float was[128], wad[128];
    int t = threadIdx.x;  // 256
    if (t < 88) {
        int h = t / 11, k = t % 11;
        float s = 0.f, d = 0.f;
        for (int c = 0; c < 128; c++) {
            float w = W1[k * 1024 + h * 128 + c];
            s += w * a1s[h * 128 + c];
            d += w * a1d[h * 128 + c];
        }
        was[h * 16 + k] = s;
        wad[h * 16 + k] = d;
    }
    __syncthreads();
    int i = blockIdx.x * 256 + t;
    if (i >= N * 8) return;
    int n = i >> 3, h = i & 7;
    float s = 0.f, d = 0.f;
#pragma unroll
    for (int k = 0; k < 11; k++) {
        float xv = x[n * 11 + k];
        s += xv * was[h * 16 + k];
        d += xv * wad[h * 16 + k];
    }
    als[i] = s;
    ald[i] = d;
}

// ------ fused layer-1 softmax + x-aggregation ------
// 128 threads: h = t>>4 (16 lanes/head), k = t&15 (x column, k<11 active).
// aggx[n, h*16+k] = bf16( sum_idx alpha[idx,h] * x[srcs[idx], k] )
__global__ void aggx_kernel(const float* __restrict__ x,
                            const float* __restrict__ als,
                            const float* __restrict__ ald,
                            const int* __restrict__ rowst,
                            const int* __restrict__ srcs,
                            unsigned short* __restrict__ A2, int N) {
    int n = blockIdx.x;
    int t = threadIdx.x;  // 128
    int h = t >> 4, k = t & 15;
    int start = rowst[n], end = rowst[n + 1];
    float aldn = ald[n * 8 + h];
    float m = -1e30f;
    for (int idx = start + k; idx < end; idx += 16) {
        float v = als[srcs[idx] * 8 + h] + aldn;
        v = v > 0.f ? v : 0.2f * v;
        m = fmaxf(m, v);
    }
#pragma unroll
    for (int o = 1; o < 16; o <<= 1) m = fmaxf(m, __shfl_xor(m, o));
    float den = 0.f;
    for (int idx = start + k; idx < end; idx += 16) {
        float v = als[srcs[idx] * 8 + h] + aldn;
        v = v > 0.f ? v : 0.2f * v;
        den += expf(v - m);
    }
#pragma unroll
    for (int o = 1; o < 16; o <<= 1) den += __shfl_xor(den, o);
    float dinv = 1.0f / (den + EPS);

    float acc = 0.f;
    const int CH = 4;
    for (int idx = start; idx < end; idx += CH) {
        int mc = end - idx;
        if (mc > CH) mc = CH;
        int ss[CH];
        float lv[CH], xv[CH];
#pragma unroll
        for (int j = 0; j < CH; j++)
            if (j < mc) ss[j] = srcs[idx + j];
#pragma unroll
        for (int j = 0; j < CH; j++)
            if (j < mc) lv[j] = als[ss[j] * 8 + h];
#pragma unroll
        for (int j = 0; j < CH; j++)
            if (j < mc) xv[j] = (k < 11) ? x[ss[j] * 11 + k] : 0.f;
#pragma unroll
        for (int j = 0; j < CH; j++)
            if (j < mc) {
                float v = lv[j] + aldn;
                v = v > 0.f ? v : 0.2f * v;
                acc += expf(v - m) * dinv * xv[j];
            }
    }
    A2[(size_t)n * 128 + t] = f2b(acc);
}

// MFMA GEMM: C[M,N] = A[M,K(lda)] * B^T. bf16 in/out, fp32 accum.
// BM=BN=128, BK=32; 4 waves, 64x64 quadrants. N%128==0, K%32==0.
// global_load_lds width=16 staging; XOR-swizzled LDS; double-buffered;
// XCD swizzle; epilogue tile unioned with staging. SK: per-col-tile
// small-K window (layer 1): A k-offset = min(16*n_t, lda-32), B tile
// = Bt + n_t*128*32 (K must be 32).
template <bool EPI, int HB, int CC, bool SK>
__global__ __launch_bounds__(256) void gemm_mfma(
    const unsigned short* __restrict__ A, const unsigned short* __restrict__ Bt,
    unsigned short* __restrict__ C, const float* __restrict__ bias,
    const float* __restrict__ a_s, const float* __restrict__ a_d,
    float* __restrict__ als, float* __restrict__ ald, int H, int M, int N,
    int K, int lda) {
    int NX = gridDim.x;
    int bid = blockIdx.y * NX + blockIdx.x;
    int win = bid & (8 * NX - 1);
    int mg = bid / (8 * NX);
    int m_t = mg * 8 + (win & 7);
    int n_t = win >> 3;
    int bm = m_t * 128, bn = n_t * 128;
    if (bm >= M) return;

    union SMem {
        struct {
            unsigned short As[2][128 * 32];
            unsigned short Bs[2][128 * 32];
        } k;                            // 32 KB, live during K-loop
        unsigned short Ct[128 * 132];   // 33.8 KB, live during epilogue
    };
    __shared__ __align__(16) SMem sm;
    auto& As = sm.k.As;
    auto& Bs = sm.k.Bs;
    auto& Ct = sm.Ct;

    int t = threadIdx.x;
    int w = t >> 6, lane = t & 63;
    int quad = lane >> 4, l16 = lane & 15;
    int wr = (w >> 1) * 64, wc = (w & 1) * 64;

    int kofs = 0;
    const unsigned short* Bb = Bt;
    if (SK) {
        kofs = n_t * 16;
        if (kofs > lda - 32) kofs = lda - 32;
        Bb = Bt + (size_t)n_t * 128 * 32;
    }

    int c0 = w * 128 + lane;
    int c1 = c0 + 64;
    int r0 = c0 >> 2, p0 = c0 & 3;
    int r1 = c1 >> 2, p1 = c1 & 3;
    int j0 = (p0 - (r0 >> 1)) & 3;
    int j1 = (p1 - (r1 >> 1)) & 3;
    int ga0 = bm + r0;
    if (ga0 >= M) ga0 = M - 1;
    int ga1 = bm + r1;
    if (ga1 >= M) ga1 = M - 1;
    const unsigned short* Ag0 = A + (size_t)ga0 * lda + kofs + j0 * 8;
    const unsigned short* Ag1 = A + (size_t)ga1 * lda + kofs + j1 * 8;
    size_t br0 = SK ? (size_t)r0 : (size_t)(bn + r0);
    size_t br1 = SK ? (size_t)r1 : (size_t)(bn + r1);
    const unsigned short* Bg0 = Bb + br0 * K + j0 * 8;
    const unsigned short* Bg1 = Bb + br1 * K + j1 * 8;

    auto stage = [&](int st, int k0) {
        load_lds16(Ag0 + k0, &As[st][(w * 128) * 8]);
        load_lds16(Ag1 + k0, &As[st][(w * 128 + 64) * 8]);
        load_lds16(Bg0 + k0, &Bs[st][(w * 128) * 8]);
        load_lds16(Bg1 + k0, &Bs[st][(w * 128 + 64) * 8]);
    };

    int aoff[4], boff4[4];
#pragma unroll
    for (int i = 0; i < 4; i++) {
        int ra = wr + i * 16 + l16;
        aoff[i] = ra * 32 + (((quad + (ra >> 1)) & 3) * 8);
        int rb = wc + i * 16 + l16;
        boff4[i] = rb * 32 + (((quad + (rb >> 1)) & 3) * 8);
    }

    f32x4 acc[4][4] = {};
    stage(0, 0);
    int st = 0;
    for (int k0 = 0; k0 < K; k0 += 32, st ^= 1) {
        __syncthreads();
        if (k0 + 32 < K) stage(st ^ 1, k0 + 32);
        short8 a[4], b[4];
#pragma unroll
        for (int mi = 0; mi < 4; mi++) a[mi] = *(const short8*)&As[st][aoff[mi]];
#pragma unroll
        for (int ni = 0; ni < 4; ni++) b[ni] = *(const short8*)&Bs[st][boff4[ni]];
#pragma unroll
        for (int mi = 0; mi < 4; mi++)
#pragma unroll
            for (int ni = 0; ni < 4; ni++)
                acc[mi][ni] = __builtin_amdgcn_mfma_f32_16x16x32_bf16(
                    a[mi], b[ni], acc[mi][ni], 0, 0, 0);
    }
    __syncthreads();  // all waves done with As/Bs before Ct overlays them

    // ---- epilogue: acc -> LDS tile (bias/act applied), then coalesced out
#pragma unroll
    for (int mi = 0; mi < 4; mi++) {
#pragma unroll
        for (int r = 0; r < 4; r++) {
            int rl = wr + mi * 16 + quad * 4 + r;
#pragma unroll
            for (int ni = 0; ni < 4; ni++) {
                int cl = wc + ni * 16 + l16;
                float v = acc[mi][ni][r];
                if (EPI) {
                    v += bias[bn + cl];
                    v = v > 0.f ? v : 0.01f * v;
                }
                Ct[rl * 132 + cl] = f2b(v);
            }
        }
    }
    __syncthreads();
    // coalesced stores: 8B chunks, 32 per row
#pragma unroll
    for (int p = 0; p < 16; p++) {
        int q = p * 256 + t;
        int row = q >> 5, c8 = q & 31;
        if (bm + row < M) {
            uint2 v = *(const uint2*)&Ct[row * 132 + c8 * 4];
            *(uint2*)&C[(size_t)(bm + row) * N + bn + c8 * 4] = v;
        }
    }
    // fused attention logits for the HB heads this col-tile covers
    if (HB > 0) {
        for (int pi = t; pi < 128 * HB; pi += 256) {
            int row = pi / HB, hl = pi % HB;
            if (bm + row >= M) continue;
            int hg = bn / CC + hl;
            const unsigned short* rp = &Ct[row * 132 + hl * CC];
            const float* asp = a_s + hg * CC;
            const float* adp = a_d + hg * CC;
            float s = 0.f, d = 0.f;
#pragma unroll
            for (int c = 0; c < CC; c++) {
                float v = b2f(rp[c]);
                s += v * asp[c];
                d += v * adp[c];
            }
            als[(size_t)(bm + row) * H + hg] = s;
            ald[(size_t)(bm + row) * H + hg] = d;
        }
    }
}

// ------ fused softmax + aggregation, ushort4 (layer 2) ------
template <int H, int C>
__global__ void agg_fused4(const unsigned short* __restrict__ hin,
                           const float* __restrict__ als,
                           const float* __restrict__ ald,
                           const int* __restrict__ rowst,
                           const int* __restrict__ srcs,
                           const float* __restrict__ bias,
                           unsigned short* __restrict__ out, int N) {
    constexpr int HC = H * C;
    constexpr int TPH = C / 4;  // 16 for C=64
    int n = blockIdx.x;
    int t = threadIdx.x;  // HC/4 threads
    int c = t * 4;
    int hh = c / C;
    int li = (c % C) / 4;
    int start = rowst[n], end = rowst[n + 1];
    float aldn = ald[n * H + hh];
    float m = -1e30f;
    for (int idx = start + li; idx < end; idx += TPH) {
        float v = als[srcs[idx] * H + hh] + aldn;
        v = v > 0.f ? v : 0.2f * v;
        m = fmaxf(m, v);
    }
#pragma unroll
    for (int o = 1; o < TPH; o <<= 1) m = fmaxf(m, __shfl_xor(m, o));
    float den = 0.f;
    for (int idx = start + li; idx < end; idx += TPH) {
        float v = als[srcs[idx] * H + hh] + aldn;
        v = v > 0.f ? v : 0.2f * v;
        den += expf(v - m);
    }
#pragma unroll
    for (int o = 1; o < TPH; o <<= 1) den += __shfl_xor(den, o);
    float dinv = 1.0f / (den + EPS);

    float a0 = 0.f, a1 = 0.f, a2 = 0.f, a3 = 0.f;
    const int CH = 4;
    for (int idx = start; idx < end; idx += CH) {
        int mc = end - idx;
        if (mc > CH) mc = CH;
        int ss[CH];
        float lv[CH];
        ushort4 uv[CH];
#pragma unroll
        for (int j = 0; j < CH; j++)
            if (j < mc) ss[j] = srcs[idx + j];
#pragma unroll
        for (int j = 0; j < CH; j++)
            if (j < mc) lv[j] = als[ss[j] * H + hh];
#pragma unroll
        for (int j = 0; j < CH; j++)
            if (j < mc) uv[j] = *(const ushort4*)(hin + (size_t)ss[j] * HC + c);
#pragma unroll
        for (int j = 0; j < CH; j++)
            if (j < mc) {
                float v = lv[j] + aldn;
                v = v > 0.f ? v : 0.2f * v;
                float a = expf(v - m) * dinv;
                a0 += a * b2f(uv[j].x);
                a1 += a * b2f(uv[j].y);
                a2 += a * b2f(uv[j].z);
                a3 += a * b2f(uv[j].w);
            }
    }
    float v0 = a0 + bias[c], v1 = a1 + bias[c + 1];
    float v2 = a2 + bias[c + 2], v3 = a3 + bias[c + 3];
    ushort4 o;
    o.x = f2b(v0 > 0.f ? v0 : 0.01f * v0);
    o.y = f2b(v1 > 0.f ? v1 : 0.01f * v1);
    o.z = f2b(v2 > 0.f ? v2 : 0.01f * v2);
    o.w = f2b(v3 > 0.f ? v3 : 0.01f * v3);
    *(ushort4*)&out[(size_t)n * HC + c] = o;
}

// ------ fused softmax + aggregation, ushort2 (layer 3) ------
template <int H, int C>
__global__ void agg_fused2(const unsigned short* __restrict__ hin,
                           const float* __restrict__ als,
                           const float* __restrict__ ald,
                           const int* __restrict__ rowst,
                           const int* __restrict__ srcs,
                           const float* __restrict__ bias,
                           unsigned short* __restrict__ out, int N) {
    constexpr int HC = H * C;
    constexpr int TPH = C / 2;  // 16 for C=32
    int n = blockIdx.x;
    int t = threadIdx.x;  // HC/2 threads
    int c = t * 2;
    int hh = c / C;
    int li = (c % C) / 2;
    int start = rowst[n], end = rowst[n + 1];
    float aldn = ald[n * H + hh];
    float m = -1e30f;
    for (int idx = start + li; idx < end; idx += TPH) {
        float v = als[srcs[idx] * H + hh] + aldn;
        v = v > 0.f ? v : 0.2f * v;
        m = fmaxf(m, v);
    }
#pragma unroll
    for (int o = 1; o < TPH; o <<= 1) m = fmaxf(m, __shfl_xor(m, o));
    float den = 0.f;
    for (int idx = start + li; idx < end; idx += TPH) {
        float v = als[srcs[idx] * H + hh] + aldn;
        v = v > 0.f ? v : 0.2f * v;
        den += expf(v - m);
    }
#pragma unroll
    for (int o = 1; o < TPH; o <<= 1) den += __shfl_xor(den, o);
    float dinv = 1.0f / (den + EPS);

    float a0 = 0.f, a1 = 0.f;
    const int CH = 4;
    for (int idx = start; idx < end; idx += CH) {
        int mc = end - idx;
        if (mc > CH) mc = CH;
        int ss[CH];
        float lv[CH];
        ushort2 uv[CH];
#pragma unroll
        for (int j = 0; j < CH; j++)
            if (j < mc) ss[j] = srcs[idx + j];
#pragma unroll
        for (int j = 0; j < CH; j++)
            if (j < mc) lv[j] = als[ss[j] * H + hh];
#pragma unroll
        for (int j = 0; j < CH; j++)
            if (j < mc) uv[j] = *(const ushort2*)(hin + (size_t)ss[j] * HC + c);
#pragma unroll
        for (int j = 0; j < CH; j++)
            if (j < mc) {
                float v = lv[j] + aldn;
                v = v > 0.f ? v : 0.2f * v;
                float a = expf(v - m) * dinv;
                a0 += a * b2f(uv[j].x);
                a1 += a * b2f(uv[j].y);
            }
    }
    float v0 = a0 + bias[c], v1 = a1 + bias[c + 1];
    ushort2 o;
    o.x = f2b(v0 > 0.f ? v0 : 0.01f * v0);
    o.y = f2b(v1 > 0.f ? v1 : 0.01f * v1);
    *(ushort2*)&out[(size_t)n * HC + c] = o;
}

// ---------------------- parallel mean-pool + head ----------------------
__global__ void pool_init_kernel(float* pool, int GC) {
    int i = blockIdx.x * blockDim.x + threadIdx.x;
    if (i < GC) pool[i] = 0.f;
}

__global__ void pool_partial_kernel(const unsigned short* __restrict__ h3,
                                    const int* __restrict__ batch,
                                    float* __restrict__ pool, int N, int G) {
    int lo = blockIdx.x * 128;
    int hi = lo + 128;
    if (hi > N) hi = N;
    if (lo >= N) return;
    int t = threadIdx.x;  // 128
    int cur = batch[lo];
    float acc = 0.f;
    for (int n = lo; n < hi; n++) {
        int g = batch[n];
        if (g != cur) {
            if ((unsigned)cur < (unsigned)G) atomicAdd(&pool[cur * 128 + t], acc);
            acc = 0.f;
            cur = g;
        }
        acc += b2f(h3[(size_t)n * 128 + t]);
    }
    if ((unsigned)cur < (unsigned)G) atomicAdd(&pool[cur * 128 + t], acc);
}

__global__ void head_kernel(const float* __restrict__ pool,
                            const int* __restrict__ batch,
                            const float* __restrict__ Wout,
                            const float* __restrict__ bout,
                            float* __restrict__ out, int N) {
    int g = blockIdx.x;
    int t = threadIdx.x;  // 128
    int lo, hi;
    {
        int a = 0, b = N;
        while (a < b) { int mid = (a + b) >> 1; if (batch[mid] < g) a = mid + 1; else b = mid; }
        lo = a;
        a = lo; b = N;
        while (a < b) { int mid = (a + b) >> 1; if (batch[mid] < g + 1) a = mid + 1; else b = mid; }
        hi = a;
    }
    float c = (float)(hi - lo);
    c = c > 1.f ? c : 1.f;
    float v = (pool[g * 128 + t] / c) * Wout[t];
    for (int o = 32; o; o >>= 1) v += __shfl_xor(v, o);
    __shared__ float partial[2];
    if ((t & 63) == 0) partial[t >> 6] = v;
    __syncthreads();
    if (t == 0) out[g] = partial[0] + partial[1] + bout[0];
}

// ---------------------------- host orchestration ----------------------------
extern "C" void kernel_launch(void* const* d_in, const int* in_sizes, int n_in,
                              void* d_out, int out_size, void* d_ws,
                              size_t ws_size, hipStream_t stream) {
    const float* x = (const float*)d_in[0];
    const int* ei = (const int*)d_in[1];
    const int* batch = (const int*)d_in[2];
    const float* W1 = (const float*)d_in[3];
    const float* a1s = (const float*)d_in[4];
    const float* a1d = (const float*)d_in[5];
    const float* b1 = (const float*)d_in[6];
    const float* W2 = (const float*)d_in[7];
    const float* a2s = (const float*)d_in[8];
    const float* a2d = (const float*)d_in[9];
    const float* b2 = (const float*)d_in[10];
    const float* W3 = (const float*)d_in[11];
    const float* a3s = (const float*)d_in[12];
    const float* a3d = (const float*)d_in[13];
    const float* b3 = (const float*)d_in[14];
    const float* Wout = (const float*)d_in[15];
    const float* bout = (const float*)d_in[16];
    float* out = (float*)d_out;

    const int N = in_sizes[0] / 11;
    const int E = in_sizes[1] / 2;
    const int Etot = E + N;
    const int G = out_size;
    const int NB = (N + 255) / 256;
    const int MT = ((N + 127) / 128 + 7) / 8 * 8;  // M-tiles padded to x8

    char* ws = (char*)d_ws;
    size_t off = 0;
    auto alloc = [&](size_t bytes) -> void* {
        void* p = ws + off;
        off += (bytes + 255) & ~(size_t)255;
        return p;
    };
    unsigned short* buf1 = (unsigned short*)alloc((size_t)N * 1024 * 2);  // h
    unsigned short* buf2 = (unsigned short*)alloc((size_t)N * 1024 * 2);  // out
    float* als = (float*)alloc((size_t)N * 8 * 4);
    float* ald = (float*)alloc((size_t)N * 8 * 4);
    int* rowst = (int*)alloc((size_t)(N + 1) * 4);
    int* cursor = (int*)alloc((size_t)N * 4);
    int* srcs = (int*)alloc((size_t)Etot * 4);  // resolved source per slot
    int* deg = (int*)alloc((size_t)N * 4);
    int* bsum = (int*)alloc((size_t)NB * 4);
    int* boff = (int*)alloc((size_t)NB * 4);
    float* pool = (float*)alloc((size_t)G * 128 * 4);
    unsigned short* aggx = (unsigned short*)alloc((size_t)N * 128 * 2);
    unsigned short* w1sk = (unsigned short*)alloc((size_t)8 * 128 * 32 * 2);
    unsigned short* wt2 = (unsigned short*)alloc((size_t)1024 * 512 * 2);
    unsigned short* wt3 = (unsigned short*)alloc((size_t)512 * 128 * 2);

    int nb = (N + 255) / 256;
    int eb = (E + 255) / 256;

    // ---- CSR by dst (self-loop at row head; srcs resolved at build) ----
    init_deg_kernel<<<nb, 256, 0, stream>>>(deg, N);
    hist_kernel<<<eb, 256, 0, stream>>>(ei, E, N, deg);
    scan_block_kernel<<<NB, 256, 0, stream>>>(deg, rowst, bsum, N);
    scan_top_kernel<<<1, 64, 0, stream>>>(bsum, boff, NB);
    scan_finish_kernel<<<NB, 256, 0, stream>>>(rowst, boff, deg, srcs, cursor,
                                               N);
    scatter_kernel<<<eb, 256, 0, stream>>>(ei, E, N, cursor, srcs);

    // ---- weight prep (one kernel) ----
    const int WTOT = 1024 * 512 + 512 * 128 + 8 * 128 * 32;
    wprep_kernel<<<(WTOT + 255) / 256, 256, 0, stream>>>(W1, W2, W3, wt2, wt3,
                                                         w1sk);

    // ---- Layer 1: logits from x, fused softmax+agg of x, small-K GEMM ----
    al1_kernel<<<(N * 8 + 255) / 256, 256, 0, stream>>>(x, W1, a1s, a1d, als,
                                                        ald, N);
    aggx_kernel<<<N, 128, 0, stream>>>(x, als, ald, rowst, srcs, aggx, N);
    gemm_mfma<true, 0, 1, true><<<dim3(8, MT), 256, 0, stream>>>(
        aggx, w1sk, buf2, b1, nullptr, nullptr, nullptr, nullptr, 0, N, 1024,
        32, 128);

    // ---- Layer 2: gemm (h2 + fused al) -> fused softmax+agg ----
    gemm_mfma<false, 2, 64, false><<<dim3(4, MT), 256, 0, stream>>>(
        buf2, wt2, buf1, nullptr, a2s, a2d, als, ald, 8, N, 512, 1024, 1024);
    agg_fused4<8, 64><<<N, 128, 0, stream>>>(buf1, als, ald, rowst, srcs, b2,
                                             buf2, N);

    // ---- Layer 3: gemm (h3 + fused al) -> fused softmax+agg ----
    gemm_mfma<false, 4, 32, false><<<dim3(1, MT), 256, 0, stream>>>(
        buf2, wt3, buf1, nullptr, a3s, a3d, als, ald, 4, N, 128, 512, 512);
    agg_fused2<4, 32><<<N, 64, 0, stream>>>(buf1, als, ald, rowst, srcs, b3,
                                            buf2, N);

    // ---- parallel mean-pool + head ----
    pool_init_kernel<<<(G * 128 + 255) / 256, 256, 0, stream>>>(pool, G * 128);
    pool_partial_kernel<<<(N + 127) / 128, 128, 0, stream>>>(buf2, batch, pool,
                                                             N, G);
    head_kernel<<<G, 128, 0, stream>>>(pool, batch, Wout, bout, out, N);
}

// Round 20
// 483.878 us; speedup vs baseline: 1.0588x; 1.0588x over previous
//
#include <hip/hip_runtime.h>

#define EPS 1e-16f

typedef __attribute__((ext_vector_type(8))) short short8;
typedef __attribute__((ext_vector_type(4))) float f32x4;

// ---------- bf16 <-> fp32 (internal storage only) ----------
__device__ __forceinline__ float b2f(unsigned short u) {
    return __uint_as_float(((unsigned)u) << 16);
}
__device__ __forceinline__ unsigned short f2b(float f) {
    unsigned u = __float_as_uint(f);
    u += 0x7fffu + ((u >> 16) & 1u);  // round-to-nearest-even
    return (unsigned short)(u >> 16);
}

// ---------- async global->LDS (16B per lane; dst = base + lane*16) ----------
typedef __attribute__((address_space(3))) void lds_vp;
typedef __attribute__((address_space(1))) const void glb_vp;
__device__ __forceinline__ void load_lds16(const unsigned short* g,
                                           unsigned short* l) {
    __builtin_amdgcn_global_load_lds((glb_vp*)g, (lds_vp*)l, 16, 0, 0);
}

// ---------------------------- CSR build ----------------------------
__global__ void init_deg_kernel(int* deg, int N) {
    int i = blockIdx.x * blockDim.x + threadIdx.x;
    if (i < N) deg[i] = 1;  // self-loop
}

__global__ void hist_kernel(const int* __restrict__ ei, int E, int N, int* deg) {
    int e = blockIdx.x * blockDim.x + threadIdx.x;
    if (e < E) {
        int d = ei[E + e];
        if ((unsigned)d < (unsigned)N) atomicAdd(&deg[d], 1);
    }
}

__global__ void scan_block_kernel(const int* __restrict__ deg,
                                  int* __restrict__ rowst,
                                  int* __restrict__ bsum, int N) {
    __shared__ int s[256];
    int t = threadIdx.x, b = blockIdx.x;
    int i = b * 256 + t;
    s[t] = (i < N) ? deg[i] : 0;
    __syncthreads();
    for (int o = 1; o < 256; o <<= 1) {
        int a = (t >= o) ? s[t - o] : 0;
        __syncthreads();
        s[t] += a;
        __syncthreads();
    }
    if (i < N) rowst[i + 1] = s[t];
    if (t == 255) bsum[b] = s[255];
}

__global__ void scan_top_kernel(const int* __restrict__ bsum,
                                int* __restrict__ boff, int NB) {
    __shared__ int psum[65];
    int t = threadIdx.x;  // 64
    int chunk = (NB + 63) / 64;
    int lo = t * chunk, hi = lo + chunk;
    if (lo > NB) lo = NB;
    if (hi > NB) hi = NB;
    int s = 0;
    for (int i = lo; i < hi; i++) s += bsum[i];
    psum[t + 1] = s;
    __syncthreads();
    if (t == 0) {
        psum[0] = 0;
        for (int i = 1; i <= 64; i++) psum[i] += psum[i - 1];
    }
    __syncthreads();
    int run = psum[t];
    for (int i = lo; i < hi; i++) {
        boff[i] = run;  // exclusive
        run += bsum[i];
    }
}

// fused: add block offsets + place self-loop + init cursor
__global__ void scan_finish_kernel(int* __restrict__ rowst,
                                   const int* __restrict__ boff,
                                   const int* __restrict__ deg,
                                   int* __restrict__ srcs,
                                   int* __restrict__ cursor, int N) {
    int i = blockIdx.x * 256 + threadIdx.x;
    if (i == 0) rowst[0] = 0;
    if (i < N) {
        int incl = rowst[i + 1] + boff[blockIdx.x];
        rowst[i + 1] = incl;
        int st = incl - deg[i];
        srcs[st] = i;  // self-loop at row head
        cursor[i] = st + 1;
    }
}

// resolve source node at CSR build time
__global__ void scatter_kernel(const int* __restrict__ ei, int E, int N,
                               int* cursor, int* srcs) {
    int e = blockIdx.x * blockDim.x + threadIdx.x;
    if (e < E) {
        int d = ei[E + e];
        if ((unsigned)d < (unsigned)N) {
            int p = atomicAdd(&cursor[d], 1);
            int s = ei[e];
            if ((unsigned)s >= (unsigned)N) s = d;
            srcs[p] = s;
        }
    }
}

// ---------------- merged weight prep: wt2, wt3, w1sk ----------------
// wt2 [512][1024] <- W2; wt3 [128][512] <- W3;
// w1sk [8][128][32]: small-K B for layer-1 (K window base = min(16h,96)).
__global__ void wprep_kernel(const float* __restrict__ W1,
                             const float* __restrict__ W2,
                             const float* __restrict__ W3,
                             unsigned short* __restrict__ wt2,
                             unsigned short* __restrict__ wt3,
                             unsigned short* __restrict__ w1sk) {
    int i = blockIdx.x * blockDim.x + threadIdx.x;
    if (i < 1024 * 512) {
        int k = i / 512, n = i % 512;
        wt2[(size_t)n * 1024 + k] = f2b(W2[i]);
    } else if (i < 1024 * 512 + 512 * 128) {
        int j = i - 1024 * 512;
        int k = j / 128, n = j % 128;
        wt3[(size_t)n * 512 + k] = f2b(W3[j]);
    } else if (i < 1024 * 512 + 512 * 128 + 8 * 128 * 32) {
        int q = i - (1024 * 512 + 512 * 128);
        int h = q >> 12, rem = q & 4095;
        int c = rem >> 5, kk = rem & 31;
        int off = (h == 7) ? 16 : 0;  // 16h - min(16h,96)
        float v = 0.f;
        int k = kk - off;
        if (k >= 0 && k < 11) v = W1[k * 1024 + h * 128 + c];
        w1sk[q] = f2b(v);
    }
}

// ---------------------------- layer-1 logits ----------------------------
__global__ void wa1_kernel(const float* __restrict__ W1,
                           const float* __restrict__ a1s,
                           const float* __restrict__ a1d,
                           float* __restrict__ w_as, float* __restrict__ w_ad) {
    int t = threadIdx.x;  // 128; active t<88
    if (t >= 88) return;
    int h = t / 11, k = t % 11;
    float s = 0.f, d = 0.f;
    for (int c = 0; c < 128; c++) {
        float w = W1[k * 1024 + h * 128 + c];
        s += w * a1s[h * 128 + c];
        d += w * a1d[h * 128 + c];
    }
    w_as[h * 16 + k] = s;
    w_ad[h * 16 + k] = d;
}

__global__ void al1_kernel(const float* __restrict__ x,
                           const float* __restrict__ w_as,
                           const float* __restrict__ w_ad,
                           float* __restrict__ als, float* __restrict__ ald,
                           int N) {
    int i = blockIdx.x * blockDim.x + threadIdx.x;
    if (i >= N * 8) return;
    int n = i >> 3, h = i & 7;
    float s = 0.f, d = 0.f;
#pragma unroll
    for (int k = 0; k < 11; k++) {
        float xv = x[n * 11 + k];
        s += xv * w_as[h * 16 + k];
        d += xv * w_ad[h * 16 + k];
    }
    als[i] = s;
    ald[i] = d;
}

// ------ layer-1 softmax: one als-gather pass; v cached in escr ------
template <int H>
__global__ void mden_kernel(const float* __restrict__ als,
                            const float* __restrict__ ald,
                            const int* __restrict__ rowst,
                            const int* __restrict__ srcs,
                            float* __restrict__ escr, int N) {
    int i = blockIdx.x * blockDim.x + threadIdx.x;
    if (i >= N * H) return;
    int n = i / H, h = i % H;
    float aldn = ald[i];
    int start = rowst[n], end = rowst[n + 1];
    const int CH = 4;
    float m = -1e30f;  // row always contains the self-loop -> real max
    for (int idx = start; idx < end; idx += CH) {
        int mc = end - idx;
        if (mc > CH) mc = CH;
        int ss[CH];
        float lv[CH];
#pragma unroll
        for (int j = 0; j < CH; j++)
            if (j < mc) ss[j] = srcs[idx + j];
#pragma unroll
        for (int j = 0; j < CH; j++)
            if (j < mc) lv[j] = als[ss[j] * H + h];
#pragma unroll
        for (int j = 0; j < CH; j++)
            if (j < mc) {
                float v = lv[j] + aldn;
                v = v > 0.f ? v : 0.2f * v;
                escr[(size_t)(idx + j) * H + h] = v;  // cache logit
                m = fmaxf(m, v);
            }
    }
    float den = 0.f;
    for (int idx = start; idx < end; idx += CH) {
        int mc = end - idx;
        if (mc > CH) mc = CH;
        float lv[CH];
#pragma unroll
        for (int j = 0; j < CH; j++)
            if (j < mc) lv[j] = escr[(size_t)(idx + j) * H + h];
#pragma unroll
        for (int j = 0; j < CH; j++)
            if (j < mc) den += expf(lv[j] - m);
    }
    float dinv = 1.0f / (den + EPS);
    for (int idx = start; idx < end; idx += CH) {
        int mc = end - idx;
        if (mc > CH) mc = CH;
        float lv[CH];
#pragma unroll
        for (int j = 0; j < CH; j++)
            if (j < mc) lv[j] = escr[(size_t)(idx + j) * H + h];
#pragma unroll
        for (int j = 0; j < CH; j++)
            if (j < mc)
                escr[(size_t)(idx + j) * H + h] = expf(lv[j] - m) * dinv;
    }
}

// aggx[n, h*16+k] = bf16( sum_idx alpha[idx,h] * x[srcs[idx], k] ), k<11
__global__ void aggx_kernel(const float* __restrict__ x,
                            const float* __restrict__ escr,
                            const int* __restrict__ rowst,
                            const int* __restrict__ srcs,
                            unsigned short* __restrict__ A2, int N) {
    int n = blockIdx.x;
    int t = threadIdx.x;  // 128
    int h = t >> 4, k = t & 15;
    int start = rowst[n], end = rowst[n + 1];
    float acc = 0.f;
    const int CH = 4;
    for (int idx = start; idx < end; idx += CH) {
        int mc = end - idx;
        if (mc > CH) mc = CH;
        int ss[CH];
        float av[CH], xv[CH];
#pragma unroll
        for (int j = 0; j < CH; j++)
            if (j < mc) ss[j] = srcs[idx + j];
#pragma unroll
        for (int j = 0; j < CH; j++)
            if (j < mc) av[j] = escr[(size_t)(idx + j) * 8 + h];
#pragma unroll
        for (int j = 0; j < CH; j++)
            if (j < mc) xv[j] = (k < 11) ? x[ss[j] * 11 + k] : 0.f;
#pragma unroll
        for (int j = 0; j < CH; j++)
            if (j < mc) acc += av[j] * xv[j];
    }
    A2[(size_t)n * 128 + t] = f2b(acc);
}

// MFMA GEMM: C[M,N] = A[M,K(lda)] * B^T. bf16 in/out, fp32 accum.
// BM=BN=128, BK=32; 4 waves, 64x64 quadrants. N%128==0, K%32==0.
// global_load_lds width=16 staging; XOR-swizzled LDS; double-buffered;
// XCD swizzle; epilogue tile unioned with staging. SK: per-col-tile
// small-K window (layer 1): A k-offset = min(16*n_t, lda-32), B tile
// = Bt + n_t*128*32 (K must be 32).
template <bool EPI, int HB, int CC, bool SK>
__global__ __launch_bounds__(256) void gemm_mfma(
    const unsigned short* __restrict__ A, const unsigned short* __restrict__ Bt,
    unsigned short* __restrict__ C, const float* __restrict__ bias,
    const float* __restrict__ a_s, const float* __restrict__ a_d,
    float* __restrict__ als, float* __restrict__ ald, int H, int M, int N,
    int K, int lda) {
    int NX = gridDim.x;
    int bid = blockIdx.y * NX + blockIdx.x;
    int win = bid & (8 * NX - 1);
    int mg = bid / (8 * NX);
    int m_t = mg * 8 + (win & 7);
    int n_t = win >> 3;
    int bm = m_t * 128, bn = n_t * 128;
    if (bm >= M) return;

    union SMem {
        struct {
            unsigned short As[2][128 * 32];
            unsigned short Bs[2][128 * 32];
        } k;                            // 32 KB, live during K-loop
        unsigned short Ct[128 * 132];   // 33.8 KB, live during epilogue
    };
    __shared__ __align__(16) SMem sm;
    auto& As = sm.k.As;
    auto& Bs = sm.k.Bs;
    auto& Ct = sm.Ct;

    int t = threadIdx.x;
    int w = t >> 6, lane = t & 63;
    int quad = lane >> 4, l16 = lane & 15;
    int wr = (w >> 1) * 64, wc = (w & 1) * 64;

    int kofs = 0;
    const unsigned short* Bb = Bt;
    if (SK) {
        kofs = n_t * 16;
        if (kofs > lda - 32) kofs = lda - 32;
        Bb = Bt + (size_t)n_t * 128 * 32;
    }

    int c0 = w * 128 + lane;
    int c1 = c0 + 64;
    int r0 = c0 >> 2, p0 = c0 & 3;
    int r1 = c1 >> 2, p1 = c1 & 3;
    int j0 = (p0 - (r0 >> 1)) & 3;
    int j1 = (p1 - (r1 >> 1)) & 3;
    int ga0 = bm + r0;
    if (ga0 >= M) ga0 = M - 1;
    int ga1 = bm + r1;
    if (ga1 >= M) ga1 = M - 1;
    const unsigned short* Ag0 = A + (size_t)ga0 * lda + kofs + j0 * 8;
    const unsigned short* Ag1 = A + (size_t)ga1 * lda + kofs + j1 * 8;
    size_t br0 = SK ? (size_t)r0 : (size_t)(bn + r0);
    size_t br1 = SK ? (size_t)r1 : (size_t)(bn + r1);
    const unsigned short* Bg0 = Bb + br0 * K + j0 * 8;
    const unsigned short* Bg1 = Bb + br1 * K + j1 * 8;

    auto stage = [&](int st, int k0) {
        load_lds16(Ag0 + k0, &As[st][(w * 128) * 8]);
        load_lds16(Ag1 + k0, &As[st][(w * 128 + 64) * 8]);
        load_lds16(Bg0 + k0, &Bs[st][(w * 128) * 8]);
        load_lds16(Bg1 + k0, &Bs[st][(w * 128 + 64) * 8]);
    };

    int aoff[4], boff4[4];
#pragma unroll
    for (int i = 0; i < 4; i++) {
        int ra = wr + i * 16 + l16;
        aoff[i] = ra * 32 + (((quad + (ra >> 1)) & 3) * 8);
        int rb = wc + i * 16 + l16;
        boff4[i] = rb * 32 + (((quad + (rb >> 1)) & 3) * 8);
    }

    f32x4 acc[4][4] = {};
    stage(0, 0);
    int st = 0;
    for (int k0 = 0; k0 < K; k0 += 32, st ^= 1) {
        __syncthreads();
        if (k0 + 32 < K) stage(st ^ 1, k0 + 32);
        short8 a[4], b[4];
#pragma unroll
        for (int mi = 0; mi < 4; mi++) a[mi] = *(const short8*)&As[st][aoff[mi]];
#pragma unroll
        for (int ni = 0; ni < 4; ni++) b[ni] = *(const short8*)&Bs[st][boff4[ni]];
#pragma unroll
        for (int mi = 0; mi < 4; mi++)
#pragma unroll
            for (int ni = 0; ni < 4; ni++)
                acc[mi][ni] = __builtin_amdgcn_mfma_f32_16x16x32_bf16(
                    a[mi], b[ni], acc[mi][ni], 0, 0, 0);
    }
    __syncthreads();  // all waves done with As/Bs before Ct overlays them

    // ---- epilogue: acc -> LDS tile (bias/act applied), then coalesced out
#pragma unroll
    for (int mi = 0; mi < 4; mi++) {
#pragma unroll
        for (int r = 0; r < 4; r++) {
            int rl = wr + mi * 16 + quad * 4 + r;
#pragma unroll
            for (int ni = 0; ni < 4; ni++) {
                int cl = wc + ni * 16 + l16;
                float v = acc[mi][ni][r];
                if (EPI) {
                    v += bias[bn + cl];
                    v = v > 0.f ? v : 0.01f * v;
                }
                Ct[rl * 132 + cl] = f2b(v);
            }
        }
    }
    __syncthreads();
    // coalesced stores: 8B chunks, 32 per row
#pragma unroll
    for (int p = 0; p < 16; p++) {
        int q = p * 256 + t;
        int row = q >> 5, c8 = q & 31;
        if (bm + row < M) {
            uint2 v = *(const uint2*)&Ct[row * 132 + c8 * 4];
            *(uint2*)&C[(size_t)(bm + row) * N + bn + c8 * 4] = v;
        }
    }
    // fused attention logits for the HB heads this col-tile covers
    if (HB > 0) {
        for (int pi = t; pi < 128 * HB; pi += 256) {
            int row = pi / HB, hl = pi % HB;
            if (bm + row >= M) continue;
            int hg = bn / CC + hl;
            const unsigned short* rp = &Ct[row * 132 + hl * CC];
            const float* asp = a_s + hg * CC;
            const float* adp = a_d + hg * CC;
            float s = 0.f, d = 0.f;
#pragma unroll
            for (int c = 0; c < CC; c++) {
                float v = b2f(rp[c]);
                s += v * asp[c];
                d += v * adp[c];
            }
            als[(size_t)(bm + row) * H + hg] = s;
            ald[(size_t)(bm + row) * H + hg] = d;
        }
    }
}

// ------ fused softmax + aggregation, ushort4 (layer 2) ------
template <int H, int C>
__global__ void agg_fused4(const unsigned short* __restrict__ hin,
                           const float* __restrict__ als,
                           const float* __restrict__ ald,
                           const int* __restrict__ rowst,
                           const int* __restrict__ srcs,
                           const float* __restrict__ bias,
                           unsigned short* __restrict__ out, int N) {
    constexpr int HC = H * C;
    constexpr int TPH = C / 4;  // 16 for C=64
    int n = blockIdx.x;
    int t = threadIdx.x;  // HC/4 threads
    int c = t * 4;
    int hh = c / C;
    int li = (c % C) / 4;
    int start = rowst[n], end = rowst[n + 1];
    float aldn = ald[n * H + hh];
    float m = -1e30f;
    for (int idx = start + li; idx < end; idx += TPH) {
        float v = als[srcs[idx] * H + hh] + aldn;
        v = v > 0.f ? v : 0.2f * v;
        m = fmaxf(m, v);
    }
#pragma unroll
    for (int o = 1; o < TPH; o <<= 1) m = fmaxf(m, __shfl_xor(m, o));
    float den = 0.f;
    for (int idx = start + li; idx < end; idx += TPH) {
        float v = als[srcs[idx] * H + hh] + aldn;
        v = v > 0.f ? v : 0.2f * v;
        den += expf(v - m);
    }
#pragma unroll
    for (int o = 1; o < TPH; o <<= 1) den += __shfl_xor(den, o);
    float dinv = 1.0f / (den + EPS);

    float a0 = 0.f, a1 = 0.f, a2 = 0.f, a3 = 0.f;
    const int CH = 4;
    for (int idx = start; idx < end; idx += CH) {
        int mc = end - idx;
        if (mc > CH) mc = CH;
        int ss[CH];
        float lv[CH];
        ushort4 uv[CH];
#pragma unroll
        for (int j = 0; j < CH; j++)
            if (j < mc) ss[j] = srcs[idx + j];
#pragma unroll
        for (int j = 0; j < CH; j++)
            if (j < mc) lv[j] = als[ss[j] * H + hh];
#pragma unroll
        for (int j = 0; j < CH; j++)
            if (j < mc) uv[j] = *(const ushort4*)(hin + (size_t)ss[j] * HC + c);
#pragma unroll
        for (int j = 0; j < CH; j++)
            if (j < mc) {
                float v = lv[j] + aldn;
                v = v > 0.f ? v : 0.2f * v;
                float a = expf(v - m) * dinv;
                a0 += a * b2f(uv[j].x);
                a1 += a * b2f(uv[j].y);
                a2 += a * b2f(uv[j].z);
                a3 += a * b2f(uv[j].w);
            }
    }
    float v0 = a0 + bias[c], v1 = a1 + bias[c + 1];
    float v2 = a2 + bias[c + 2], v3 = a3 + bias[c + 3];
    ushort4 o;
    o.x = f2b(v0 > 0.f ? v0 : 0.01f * v0);
    o.y = f2b(v1 > 0.f ? v1 : 0.01f * v1);
    o.z = f2b(v2 > 0.f ? v2 : 0.01f * v2);
    o.w = f2b(v3 > 0.f ? v3 : 0.01f * v3);
    *(ushort4*)&out[(size_t)n * HC + c] = o;
}

// ------ fused softmax + aggregation, ushort2 (layer 3) ------
template <int H, int C>
__global__ void agg_fused2(const unsigned short* __restrict__ hin,
                           const float* __restrict__ als,
                           const float* __restrict__ ald,
                           const int* __restrict__ rowst,
                           const int* __restrict__ srcs,
                           const float* __restrict__ bias,
                           unsigned short* __restrict__ out, int N) {
    constexpr int HC = H * C;
    constexpr int TPH = C / 2;  // 16 for C=32
    int n = blockIdx.x;
    int t = threadIdx.x;  // HC/2 threads
    int c = t * 2;
    int hh = c / C;
    int li = (c % C) / 2;
    int start = rowst[n], end = rowst[n + 1];
    float aldn = ald[n * H + hh];
    float m = -1e30f;
    for (int idx = start + li; idx < end; idx += TPH) {
        float v = als[srcs[idx] * H + hh] + aldn;
        v = v > 0.f ? v : 0.2f * v;
        m = fmaxf(m, v);
    }
#pragma unroll
    for (int o = 1; o < TPH; o <<= 1) m = fmaxf(m, __shfl_xor(m, o));
    float den = 0.f;
    for (int idx = start + li; idx < end; idx += TPH) {
        float v = als[srcs[idx] * H + hh] + aldn;
        v = v > 0.f ? v : 0.2f * v;
        den += expf(v - m);
    }
#pragma unroll
    for (int o = 1; o < TPH; o <<= 1) den += __shfl_xor(den, o);
    float dinv = 1.0f / (den + EPS);

    float a0 = 0.f, a1 = 0.f;
    const int CH = 4;
    for (int idx = start; idx < end; idx += CH) {
        int mc = end - idx;
        if (mc > CH) mc = CH;
        int ss[CH];
        float lv[CH];
        ushort2 uv[CH];
#pragma unroll
        for (int j = 0; j < CH; j++)
            if (j < mc) ss[j] = srcs[idx + j];
#pragma unroll
        for (int j = 0; j < CH; j++)
            if (j < mc) lv[j] = als[ss[j] * H + hh];
#pragma unroll
        for (int j = 0; j < CH; j++)
            if (j < mc) uv[j] = *(const ushort2*)(hin + (size_t)ss[j] * HC + c);
#pragma unroll
        for (int j = 0; j < CH; j++)
            if (j < mc) {
                float v = lv[j] + aldn;
                v = v > 0.f ? v : 0.2f * v;
                float a = expf(v - m) * dinv;
                a0 += a * b2f(uv[j].x);
                a1 += a * b2f(uv[j].y);
            }
    }
    float v0 = a0 + bias[c], v1 = a1 + bias[c + 1];
    ushort2 o;
    o.x = f2b(v0 > 0.f ? v0 : 0.01f * v0);
    o.y = f2b(v1 > 0.f ? v1 : 0.01f * v1);
    *(ushort2*)&out[(size_t)n * HC + c] = o;
}

// ---------------------- parallel mean-pool + head ----------------------
__global__ void pool_init_kernel(float* pool, int GC) {
    int i = blockIdx.x * blockDim.x + threadIdx.x;
    if (i < GC) pool[i] = 0.f;
}

__global__ void pool_partial_kernel(const unsigned short* __restrict__ h3,
                                    const int* __restrict__ batch,
                                    float* __restrict__ pool, int N, int G) {
    int lo = blockIdx.x * 128;
    int hi = lo + 128;
    if (hi > N) hi = N;
    if (lo >= N) return;
    int t = threadIdx.x;  // 128
    int cur = batch[lo];
    float acc = 0.f;
    for (int n = lo; n < hi; n++) {
        int g = batch[n];
        if (g != cur) {
            if ((unsigned)cur < (unsigned)G) atomicAdd(&pool[cur * 128 + t], acc);
            acc = 0.f;
            cur = g;
        }
        acc += b2f(h3[(size_t)n * 128 + t]);
    }
    if ((unsigned)cur < (unsigned)G) atomicAdd(&pool[cur * 128 + t], acc);
}

__global__ void head_kernel(const float* __restrict__ pool,
                            const int* __restrict__ batch,
                            const float* __restrict__ Wout,
                            const float* __restrict__ bout,
                            float* __restrict__ out, int N) {
    int g = blockIdx.x;
    int t = threadIdx.x;  // 128
    int lo, hi;
    {
        int a = 0, b = N;
        while (a < b) { int mid = (a + b) >> 1; if (batch[mid] < g) a = mid + 1; else b = mid; }
        lo = a;
        a = lo; b = N;
        while (a < b) { int mid = (a + b) >> 1; if (batch[mid] < g + 1) a = mid + 1; else b = mid; }
        hi = a;
    }
    float c = (float)(hi - lo);
    c = c > 1.f ? c : 1.f;
    float v = (pool[g * 128 + t] / c) * Wout[t];
    for (int o = 32; o; o >>= 1) v += __shfl_xor(v, o);
    __shared__ float partial[2];
    if ((t & 63) == 0) partial[t >> 6] = v;
    __syncthreads();
    if (t == 0) out[g] = partial[0] + partial[1] + bout[0];
}

// ---------------------------- host orchestration ----------------------------
extern "C" void kernel_launch(void* const* d_in, const int* in_sizes, int n_in,
                              void* d_out, int out_size, void* d_ws,
                              size_t ws_size, hipStream_t stream) {
    const float* x = (const float*)d_in[0];
    const int* ei = (const int*)d_in[1];
    const int* batch = (const int*)d_in[2];
    const float* W1 = (const float*)d_in[3];
    const float* a1s = (const float*)d_in[4];
    const float* a1d = (const float*)d_in[5];
    const float* b1 = (const float*)d_in[6];
    const float* W2 = (const float*)d_in[7];
    const float* a2s = (const float*)d_in[8];
    const float* a2d = (const float*)d_in[9];
    const float* b2 = (const float*)d_in[10];
    const float* W3 = (const float*)d_in[11];
    const float* a3s = (const float*)d_in[12];
    const float* a3d = (const float*)d_in[13];
    const float* b3 = (const float*)d_in[14];
    const float* Wout = (const float*)d_in[15];
    const float* bout = (const float*)d_in[16];
    float* out = (float*)d_out;

    const int N = in_sizes[0] / 11;
    const int E = in_sizes[1] / 2;
    const int Etot = E + N;
    const int G = out_size;
    const int NB = (N + 255) / 256;
    const int MT = ((N + 127) / 128 + 7) / 8 * 8;  // M-tiles padded to x8

    char* ws = (char*)d_ws;
    size_t off = 0;
    auto alloc = [&](size_t bytes) -> void* {
        void* p = ws + off;
        off += (bytes + 255) & ~(size_t)255;
        return p;
    };
    unsigned short* buf1 = (unsigned short*)alloc((size_t)N * 1024 * 2);  // h
    unsigned short* buf2 = (unsigned short*)alloc((size_t)N * 1024 * 2);  // out
    float* als = (float*)alloc((size_t)N * 8 * 4);
    float* ald = (float*)alloc((size_t)N * 8 * 4);
    float* escr = (float*)alloc((size_t)Etot * 8 * 4);  // layer-1 alpha
    int* rowst = (int*)alloc((size_t)(N + 1) * 4);
    int* cursor = (int*)alloc((size_t)N * 4);
    int* srcs = (int*)alloc((size_t)Etot * 4);
    int* deg = (int*)alloc((size_t)N * 4);
    int* bsum = (int*)alloc((size_t)NB * 4);
    int* boff = (int*)alloc((size_t)NB * 4);
    float* pool = (float*)alloc((size_t)G * 128 * 4);
    unsigned short* aggx = (unsigned short*)alloc((size_t)N * 128 * 2);
    unsigned short* w1sk = (unsigned short*)alloc((size_t)8 * 128 * 32 * 2);
    unsigned short* wt2 = (unsigned short*)alloc((size_t)1024 * 512 * 2);
    unsigned short* wt3 = (unsigned short*)alloc((size_t)512 * 128 * 2);
    float* w_as = (float*)alloc(8 * 16 * 4);
    float* w_ad = (float*)alloc(8 * 16 * 4);

    int nb = (N + 255) / 256;
    int eb = (E + 255) / 256;

    // ---- CSR by dst (self-loop at row head; srcs resolved at build) ----
    init_deg_kernel<<<nb, 256, 0, stream>>>(deg, N);
    hist_kernel<<<eb, 256, 0, stream>>>(ei, E, N, deg);
    scan_block_kernel<<<NB, 256, 0, stream>>>(deg, rowst, bsum, N);
    scan_top_kernel<<<1, 64, 0, stream>>>(bsum, boff, NB);
    scan_finish_kernel<<<NB, 256, 0, stream>>>(rowst, boff, deg, srcs, cursor,
                                               N);
    scatter_kernel<<<eb, 256, 0, stream>>>(ei, E, N, cursor, srcs);

    // ---- weight prep ----
    const int WTOT = 1024 * 512 + 512 * 128 + 8 * 128 * 32;
    wprep_kernel<<<(WTOT + 255) / 256, 256, 0, stream>>>(W1, W2, W3, wt2, wt3,
                                                         w1sk);
    wa1_kernel<<<1, 128, 0, stream>>>(W1, a1s, a1d, w_as, w_ad);

    // ---- Layer 1 (linearity trick) ----
    al1_kernel<<<(N * 8 + 255) / 256, 256, 0, stream>>>(x, w_as, w_ad, als, ald,
                                                        N);
    mden_kernel<8><<<(N * 8 + 255) / 256, 256, 0, stream>>>(als, ald, rowst,
                                                            srcs, escr, N);
    aggx_kernel<<<N, 128, 0, stream>>>(x, escr, rowst, srcs, aggx, N);
    gemm_mfma<true, 0, 1, true><<<dim3(8, MT), 256, 0, stream>>>(
        aggx, w1sk, buf2, b1, nullptr, nullptr, nullptr, nullptr, 0, N, 1024,
        32, 128);

    // ---- Layer 2: gemm (h2 + fused al) -> fused softmax+agg ----
    gemm_mfma<false, 2, 64, false><<<dim3(4, MT), 256, 0, stream>>>(
        buf2, wt2, buf1, nullptr, a2s, a2d, als, ald, 8, N, 512, 1024, 1024);
    agg_fused4<8, 64><<<N, 128, 0, stream>>>(buf1, als, ald, rowst, srcs, b2,
                                             buf2, N);

    // ---- Layer 3: gemm (h3 + fused al) -> fused softmax+agg ----
    gemm_mfma<false, 4, 32, false><<<dim3(1, MT), 256, 0, stream>>>(
        buf2, wt3, buf1, nullptr, a3s, a3d, als, ald, 4, N, 128, 512, 512);
    agg_fused2<4, 32><<<N, 64, 0, stream>>>(buf1, als, ald, rowst, srcs, b3,
                                            buf2, N);

    // ---- parallel mean-pool + head ----
    pool_init_kernel<<<(G * 128 + 255) / 256, 256, 0, stream>>>(pool, G * 128);
    pool_partial_kernel<<<(N + 127) / 128, 128, 0, stream>>>(buf2, batch, pool,
                                                             N, G);
    head_kernel<<<G, 128, 0, stream>>>(pool, batch, Wout, bout, out, N);
}